// Round 17
// baseline (721.070 us; speedup 1.0000x reference)
//
#include <hip/hip_runtime.h>
#include <hip/hip_bf16.h>
#include <math.h>

// Problem constants (fixed by the reference)
#define NN 50000
#define EE 400000
#define TT 4
#define DIN 64
#define DD 128
#define BB 64
#define STEPS 8
#define KAGG 544    // 512 (T*D) + 4 (per-type counts for b_msg) + 28 pad -> 17*32
#define NGATES 512  // [r_sum, z_sum, i_n, h_n]
#define NBIN (4 * NN)             // (dst, etype) bins
#define NBLK ((NBIN + 255) / 256) // 782 scan blocks
#define MT64 ((NN + 63) / 64)     // 782 step blocks
#define W2F_N (21 * 12288)        // fragment-ordered W2: [kc][gb][wave][lane][8]
#define PREP_G (544 * 48)         // g-part octet threads (k x n-octet)
#define PREP_H (4 * 12288)        // h-part element threads
#define PREP_TOT (PREP_G + PREP_H + NGATES)

typedef __attribute__((ext_vector_type(8))) short bf16x8;
typedef __attribute__((ext_vector_type(4))) float f32x4;
typedef __attribute__((address_space(3))) void lds_void;
typedef __attribute__((address_space(1))) void glob_void;

__device__ inline float bf2f(__hip_bfloat16 x) { return __bfloat162float(x); }

// exact bf16(bit pattern in short) -> f32, value-based (vector elements have no address)
__device__ inline float s2f(short s) {
    unsigned int u = ((unsigned int)(unsigned short)s) << 16;
    float f;
    __builtin_memcpy(&f, &u, 4);
    return f;
}

// ---------------------------------------------------------------- init (zero-pad 64->128)
__global__ void k_init_h(const float* __restrict__ feat, float* __restrict__ h1,
                         __hip_bfloat16* __restrict__ hb) {
    int idx = blockIdx.x * blockDim.x + threadIdx.x;
    if (idx >= NN * DD) return;
    int v = idx >> 7, d = idx & 127;
    float val = (d < DIN) ? feat[v * DIN + d] : 0.0f;
    h1[idx] = val;
    hb[idx] = __float2bfloat16(val);
}

// one launch zeroes both deg2 and feats
__global__ void k_zero2(int* __restrict__ deg2, float* __restrict__ feats) {
    int idx = blockIdx.x * blockDim.x + threadIdx.x;
    if (idx < NBIN) deg2[idx] = 0;
    else if (idx < NBIN + BB * DD) feats[idx - NBIN] = 0.0f;
}

// ---------------------------------------------------------------- CSR build by (dst,type)
__global__ void k_hist(const int* __restrict__ dst, const int* __restrict__ etype,
                       int* __restrict__ deg2) {
    int e = blockIdx.x * blockDim.x + threadIdx.x;
    if (e < EE) atomicAdd(&deg2[dst[e] * 4 + etype[e]], 1);
}

__global__ __launch_bounds__(256) void k_scan_bsum(const int* __restrict__ deg2,
                                                   int* __restrict__ bsum) {
    __shared__ int red[256];
    int tid = threadIdx.x;
    int i = blockIdx.x * 256 + tid;
    int v = (i < NBIN) ? deg2[i] : 0;
    red[tid] = v;
    __syncthreads();
#pragma unroll
    for (int s = 128; s > 0; s >>= 1) {
        if (tid < s) red[tid] += red[tid + s];
        __syncthreads();
    }
    if (tid == 0) bsum[blockIdx.x] = red[0];
}

__global__ __launch_bounds__(1024) void k_scan_boff(const int* __restrict__ bsum,
                                                    int* __restrict__ boff) {
    __shared__ int s[1024];
    int tid = threadIdx.x;
    int v = (tid < NBLK) ? bsum[tid] : 0;
    s[tid] = v;
    __syncthreads();
    for (int d = 1; d < 1024; d <<= 1) {
        int t = (tid >= d) ? s[tid - d] : 0;
        __syncthreads();
        s[tid] += t;
        __syncthreads();
    }
    if (tid < NBLK) boff[tid] = s[tid] - v;  // exclusive
}

// scan_final also writes g's count columns (cols 512..515 = deg2 value, already in
// a register here) and zeroes the pad cols 516..543 -- replaces the k_counts launch.
__global__ __launch_bounds__(256) void k_scan_final(const int* __restrict__ deg2,
                                                    const int* __restrict__ boff,
                                                    int* __restrict__ off2,
                                                    int* __restrict__ cursor,
                                                    __hip_bfloat16* __restrict__ g) {
    __shared__ int s[256];
    int tid = threadIdx.x;
    int i = blockIdx.x * 256 + tid;
    int v = (i < NBIN) ? deg2[i] : 0;
    s[tid] = v;
    __syncthreads();
#pragma unroll
    for (int d = 1; d < 256; d <<= 1) {
        int t = (tid >= d) ? s[tid - d] : 0;
        __syncthreads();
        s[tid] += t;
        __syncthreads();
    }
    int excl = boff[blockIdx.x] + s[tid] - v;
    if (i < NBIN) {
        off2[i] = excl;
        cursor[i] = excl;
        if (i == NBIN - 1) off2[NBIN] = excl + v;  // == EE
        // counts + pad columns of g (constant across steps)
        int node = i >> 2, t = i & 3;
        __hip_bfloat16* grow = g + (size_t)node * KAGG + 512;
        grow[t] = __float2bfloat16((float)v);
        __hip_bfloat16 z = __float2bfloat16(0.0f);
#pragma unroll
        for (int p = 0; p < 7; ++p) grow[4 + t * 7 + p] = z;  // cols 516..543
    }
}

__global__ void k_fill(const int* __restrict__ dst, const int* __restrict__ src,
                       const int* __restrict__ etype, int* __restrict__ cursor,
                       int* __restrict__ csr_src) {
    int e = blockIdx.x * blockDim.x + threadIdx.x;
    if (e < EE) {
        int pos = atomicAdd(&cursor[dst[e] * 4 + etype[e]], 1);
        csr_src[pos] = src[e];
    }
}

// ---------------------------------------------------------------- weight prep (once/call)
// Fragment-ordered composed weights W2f[kc][gb][wave][lane][8] bf16 (see round-12 notes).
// v2: g-part computed OCTET-wise -- one thread does 8 consecutive n for a fixed k:
// wr[e] loaded once (contiguous scalar), wih[e*384+n0..n0+7] as two float4 loads.
// 8x fewer threads, ~5x fewer load instructions for the composed dot products.
__global__ __launch_bounds__(256) void k_prep_w2f(const float* __restrict__ Wm,
                                                  const float* __restrict__ bm,
                                                  const float* __restrict__ wih,
                                                  const float* __restrict__ whh,
                                                  const float* __restrict__ bih,
                                                  const float* __restrict__ bhh,
                                                  __hip_bfloat16* __restrict__ W2f,
                                                  float* __restrict__ bias512) {
    int idx = blockIdx.x * blockDim.x + threadIdx.x;
    if (idx < PREP_G) {
        // g-part: k in 0..543, n-octet in 0..47 (n0 = oct*8)
        const int k = idx / 48;
        const int n0 = (idx % 48) * 8;
        float s[8];
#pragma unroll
        for (int j = 0; j < 8; ++j) s[j] = 0.0f;
        const float* wr = nullptr;
        if (k < 512) {
            int t = k >> 7, kd = k & 127;
            wr = Wm + (t << 14) + (kd << 7);
        } else if (k < 516) {
            wr = bm + ((k - 512) << 7);
        }
        if (wr) {
#pragma unroll 4
            for (int e = 0; e < 128; ++e) {
                const float w = wr[e];
                const f32x4 a = *(const f32x4*)(wih + e * 384 + n0);
                const f32x4 b = *(const f32x4*)(wih + e * 384 + n0 + 4);
                s[0] += w * a[0]; s[1] += w * a[1]; s[2] += w * a[2]; s[3] += w * a[3];
                s[4] += w * b[0]; s[5] += w * b[1]; s[6] += w * b[2]; s[7] += w * b[3];
            }
        }
        // scatter into fragment layout: idx_j = kc*12288 + gb*4096 + w*512 + (lhi*16+m)*8 + jk
        const int kc = k >> 5;
        const int kin = k & 31;
        const int lhi = kin >> 3;
        const int jk = kin & 7;
#pragma unroll
        for (int j = 0; j < 8; ++j) {
            const int n = n0 + j;
            const int gb = n >> 7;
            const int within = n & 127;
            const int w = within >> 4;
            const int m = within & 15;
            W2f[kc * 12288 + gb * 4096 + w * 512 + (lhi * 16 + m) * 8 + jk] =
                __float2bfloat16(s[j]);
        }
        return;
    }
    int idx2 = idx - PREP_G;
    if (idx2 < PREP_H) {
        // h-part (kc 17..20): plain per-element copy of w_hh into fragment layout
        const int kc = 17 + idx2 / 12288;
        const int r1 = idx2 % 12288;
        const int gb = r1 >> 12;
        const int r2 = r1 & 4095;
        const int w = r2 >> 9;
        const int r3 = r2 & 511;
        const int l = r3 >> 3;
        const int j = r3 & 7;
        const int npart = w * 16 + (l & 15);
        const int kin = ((l >> 4) << 3) + j;
        const int kh = (kc - 17) * 32 + kin;                         // 0..127
        const int nlog = (gb < 2) ? gb * 128 + npart : 384 + npart;  // r,z,h_n
        const int col = (nlog < 256) ? nlog : nlog - 128;            // w_hh col
        W2f[kc * 12288 + r1] = __float2bfloat16(whh[kh * 384 + col]);
        return;
    }
    int b = idx2 - PREP_H;
    if (b < NGATES) {
        float v;
        if (b < 256) v = bih[b] + bhh[b];
        else if (b < 384) v = bih[b];
        else v = bhh[b - 128];
        bias512[b] = v;
    }
}

// ---------------------------------------------------------------- per-type aggregation v3
// One WAVE per node; 4x 16-lane GROUPS walk the node's 4 type-lists CONCURRENTLY.
// Gather-chain collapse: lane sub loads csr_src[base+sub] (16 indices per instr),
// __shfl broadcasts index r to its group -> all h-row loads are address-independent
// and issue back-to-back (chain depth ~2 latencies instead of cnt).
__global__ __launch_bounds__(256) void k_agg(const __hip_bfloat16* __restrict__ hb,
                                             const int* __restrict__ off2,
                                             const int* __restrict__ csr_src,
                                             __hip_bfloat16* __restrict__ g) {
    const int node = (blockIdx.x * blockDim.x + threadIdx.x) >> 6;
    const int lane = threadIdx.x & 63;
    if (node >= NN) return;
    const int t = lane >> 4;      // group = etype
    const int sub = lane & 15;    // 8 dims per lane
    const int gbase = lane & 48;  // group's lane base for shfl
    const int p0 = off2[4 * node + t];
    const int p1 = off2[4 * node + t + 1];
    float a[8];
#pragma unroll
    for (int j = 0; j < 8; ++j) a[j] = 0.0f;
    for (int base = p0; base < p1; base += 16) {
        int cnt = p1 - base;
        if (cnt > 16) cnt = 16;
        int idxv = (sub < cnt) ? csr_src[base + sub] : 0;
        int r = 0;
        for (; r + 1 < cnt; r += 2) {
            int s0 = __shfl(idxv, gbase + r);
            int s1 = __shfl(idxv, gbase + r + 1);
            bf16x8 v0 = *(const bf16x8*)(hb + (size_t)s0 * DD + sub * 8);
            bf16x8 v1 = *(const bf16x8*)(hb + (size_t)s1 * DD + sub * 8);
#pragma unroll
            for (int j = 0; j < 8; ++j) a[j] += s2f(v0[j]) + s2f(v1[j]);
        }
        if (r < cnt) {
            int s0 = __shfl(idxv, gbase + r);
            bf16x8 v0 = *(const bf16x8*)(hb + (size_t)s0 * DD + sub * 8);
#pragma unroll
            for (int j = 0; j < 8; ++j) a[j] += s2f(v0[j]);
        }
    }
    bf16x8 o;
#pragma unroll
    for (int j = 0; j < 8; ++j) {
        __hip_bfloat16 b = __float2bfloat16(a[j]);
        o[j] = *(short*)&b;
    }
    *(bf16x8*)(g + (size_t)node * KAGG + t * 128 + sub * 8) = o;
}

// ---------------------------------------------------------------- fused step kernel (v7b)
// (round-15 verified: 48.5 us) A through LDS (2-buffer ping-pong, global_load_lds
// + swizzle). B direct global->register from fragment-ordered W2f, issued FIRST
// after the barrier (L2 latency heads the chain). One barrier per chunk.
__global__ __launch_bounds__(512, 4) void k_step(const __hip_bfloat16* __restrict__ g,
                                                 const __hip_bfloat16* __restrict__ W2f,
                                                 const float* __restrict__ bias512,
                                                 const __hip_bfloat16* __restrict__ hbi,
                                                 __hip_bfloat16* __restrict__ hbo) {
    __shared__ __align__(16) short As[2][64 * 32];  // 2 x 4 KB ping-pong
    __shared__ __align__(16) short Ht[64 * 132];    // 16.9 KB epilogue stage
    const int tid = threadIdx.x;
    const int lane = tid & 63;
    const int wave = tid >> 6;
    const int row0 = blockIdx.x * 64;
    const int quad = lane >> 4;
    const int m16 = lane & 15;
    const int koff = ((quad ^ ((m16 ^ (m16 >> 2)) & 3)) << 3);  // A swizzle (shorts)

    // A staging mapping (waves 0..3; slot = tid < 256)
    const int arow = tid >> 2;
    const int apart = (tid & 3) ^ ((arow ^ (arow >> 2)) & 3);
    int agrow = row0 + arow;
    if (agrow >= NN) agrow = NN - 1;
    const __hip_bfloat16* gA = g + (size_t)agrow * KAGG + apart * 8;
    const __hip_bfloat16* hA = hbi + (size_t)agrow * DD + apart * 8;
    const __hip_bfloat16* bw = W2f + ((size_t)(wave * 64 + lane)) * 8;  // own fragment base

    auto stage_A = [&](int kc) {
        if (wave < 4) {
            const glob_void* srcA = (kc < 17)
                                        ? (const glob_void*)(gA + kc * 32)
                                        : (const glob_void*)(hA + (kc - 17) * 32);
            __builtin_amdgcn_global_load_lds(srcA, (lds_void*)&As[kc & 1][(wave * 64) * 8],
                                             16, 0, 0);
        }
    };

    f32x4 acc[4][4];  // [row-tile][gate: r,z,in,hn]
#pragma unroll
    for (int rt = 0; rt < 4; ++rt)
#pragma unroll
        for (int c = 0; c < 4; ++c) acc[rt][c] = (f32x4){0.f, 0.f, 0.f, 0.f};

    stage_A(0);
    __syncthreads();

    for (int ki = 0; ki < 21; ++ki) {
        // B first: direct global->register, own contiguous 1KB fragments (L2-hot).
        const __hip_bfloat16* bp = bw + ki * 12288;
        bf16x8 b0 = *(const bf16x8*)(bp);
        bf16x8 b1 = *(const bf16x8*)(bp + 4096);
        bf16x8 b2 = *(const bf16x8*)(bp + 8192);

        if (ki + 1 < 21) stage_A(ki + 1);

        bf16x8 af[4];
#pragma unroll
        for (int rt = 0; rt < 4; ++rt)
            af[rt] = *(const bf16x8*)&As[ki & 1][(rt * 16 + m16) * 32 + koff];
#pragma unroll
        for (int rt = 0; rt < 4; ++rt)
            acc[rt][0] = __builtin_amdgcn_mfma_f32_16x16x32_bf16(af[rt], b0, acc[rt][0], 0, 0, 0);
#pragma unroll
        for (int rt = 0; rt < 4; ++rt)
            acc[rt][1] = __builtin_amdgcn_mfma_f32_16x16x32_bf16(af[rt], b1, acc[rt][1], 0, 0, 0);
        if (ki < 17) {
#pragma unroll
            for (int rt = 0; rt < 4; ++rt)
                acc[rt][2] = __builtin_amdgcn_mfma_f32_16x16x32_bf16(af[rt], b2, acc[rt][2], 0, 0, 0);
        } else {
#pragma unroll
            for (int rt = 0; rt < 4; ++rt)
                acc[rt][3] = __builtin_amdgcn_mfma_f32_16x16x32_bf16(af[rt], b2, acc[rt][3], 0, 0, 0);
        }
        __syncthreads();  // drains stage_A(ki+1); As[ki&1] free for reuse next iter
    }

    // ---------------- epilogue: in-register GRU -> LDS (stride 132) -> full-line store
    {
        const int d = wave * 16 + m16;
        const float brs = bias512[d];
        const float bzs = bias512[128 + d];
        const float bin_ = bias512[256 + d];
        const float bhn = bias512[384 + d];
#pragma unroll
        for (int rt = 0; rt < 4; ++rt) {
#pragma unroll
            for (int j = 0; j < 4; ++j) {
                const int rowl = rt * 16 + quad * 4 + j;
                const int grow = row0 + rowl;
                const float rs = acc[rt][0][j] + brs;
                const float zs = acc[rt][1][j] + bzs;
                const float inn = acc[rt][2][j] + bin_;
                const float hnn = acc[rt][3][j] + bhn;
                const float rr = 1.0f / (1.0f + __expf(-rs));
                const float zz = 1.0f / (1.0f + __expf(-zs));
                const float ex = __expf(2.0f * (inn + rr * hnn));
                const float ng = 1.0f - 2.0f / (ex + 1.0f);  // tanh, overflow-safe
                const float hv =
                    bf2f(hbi[(size_t)(grow < NN ? grow : NN - 1) * DD + d]);
                const float o = (1.0f - zz) * ng + zz * hv;
                __hip_bfloat16 ob = __float2bfloat16(o);
                Ht[rowl * 132 + d] = *(short*)&ob;
            }
        }
    }
    __syncthreads();
    {
        // 512 threads x 32 B contiguous -> fully-coalesced full-line stores
        const int row = tid >> 3;
        const int col = (tid & 7) * 16;
        if (row0 + row < NN) {
            bf16x8 v0 = *(const bf16x8*)&Ht[row * 132 + col];
            bf16x8 v1 = *(const bf16x8*)&Ht[row * 132 + col + 8];
            __hip_bfloat16* dstp = hbo + (size_t)(row0 + row) * DD + col;
            *(bf16x8*)dstp = v0;
            *(bf16x8*)(dstp + 8) = v1;
        }
    }
}

// ---------------------------------------------------------------- readout (n2g is sorted)
__global__ __launch_bounds__(128) void k_readout(const __hip_bfloat16* __restrict__ h,
                                                 const float* __restrict__ h1,
                                                 const int* __restrict__ n2g,
                                                 float* __restrict__ feats) {
    const int CHN = 64;
    int d = threadIdx.x;
    int v0 = blockIdx.x * CHN;
    if (v0 >= NN) return;
    int v1 = v0 + CHN;
    if (v1 > NN) v1 = NN;
    float sum = 0.0f;
    int cur = n2g[v0];
    for (int v = v0; v < v1; ++v) {
        int gph = n2g[v];
        if (gph != cur) {
            atomicAdd(&feats[cur * DD + d], sum);
            sum = 0.0f;
            cur = gph;
        }
        sum += bf2f(h[(size_t)v * DD + d]) + h1[(size_t)v * DD + d];
    }
    atomicAdd(&feats[cur * DD + d], sum);
}

// ---------------------------------------------------------------- classifier
__global__ void k_cls(const float* __restrict__ feats, const float* __restrict__ Wc,
                      const float* __restrict__ bc, float* __restrict__ out) {
    int t = threadIdx.x;
    if (t >= BB * 2) return;
    int b = t >> 1, c = t & 1;
    float s = bc[c];
    for (int d = 0; d < DD; ++d) s += feats[b * DD + d] * Wc[d * 2 + c];
    out[t] = s;
}

// ================================================================ launcher
extern "C" void kernel_launch(void* const* d_in, const int* in_sizes, int n_in, void* d_out,
                              int out_size, void* d_ws, size_t ws_size, hipStream_t stream) {
    const float* features = (const float*)d_in[0];
    const int* src = (const int*)d_in[1];
    const int* dst = (const int*)d_in[2];
    const int* etype = (const int*)d_in[3];
    const int* n2g = (const int*)d_in[4];
    const float* W_msg = (const float*)d_in[5];
    const float* b_msg = (const float*)d_in[6];
    const float* w_ih = (const float*)d_in[7];
    const float* b_ih = (const float*)d_in[8];
    const float* w_hh = (const float*)d_in[9];
    const float* b_hh = (const float*)d_in[10];
    const float* W_cls = (const float*)d_in[11];
    const float* b_cls = (const float*)d_in[12];
    float* out = (float*)d_out;

    char* ws = (char*)d_ws;
    size_t o = 0;
    auto alloc = [&](size_t bytes) {
        o = (o + 255) & ~(size_t)255;
        void* p = ws + o;
        o += bytes;
        return p;
    };
    int* deg2 = (int*)alloc(sizeof(int) * NBIN);
    int* off2 = (int*)alloc(sizeof(int) * (NBIN + 1));
    int* cursor = (int*)alloc(sizeof(int) * NBIN);
    int* bsum = (int*)alloc(sizeof(int) * NBLK);
    int* boff = (int*)alloc(sizeof(int) * NBLK);
    int* csr_src = (int*)alloc(sizeof(int) * EE);
    __hip_bfloat16* W2f = (__hip_bfloat16*)alloc(sizeof(__hip_bfloat16) * W2F_N);
    float* bias512 = (float*)alloc(sizeof(float) * NGATES);
    float* hini = (float*)alloc(sizeof(float) * (size_t)NN * DD);
    __hip_bfloat16* hbfA = (__hip_bfloat16*)alloc(sizeof(__hip_bfloat16) * (size_t)NN * DD);
    __hip_bfloat16* hbfB = (__hip_bfloat16*)alloc(sizeof(__hip_bfloat16) * (size_t)NN * DD);
    __hip_bfloat16* g = (__hip_bfloat16*)alloc(sizeof(__hip_bfloat16) * (size_t)NN * KAGG);
    float* feats = (float*)alloc(sizeof(float) * BB * DD);

    // setup
    k_init_h<<<(NN * DD + 255) / 256, 256, 0, stream>>>(features, hini, hbfA);
    k_zero2<<<(NBIN + BB * DD + 255) / 256, 256, 0, stream>>>(deg2, feats);
    k_hist<<<(EE + 255) / 256, 256, 0, stream>>>(dst, etype, deg2);
    k_scan_bsum<<<NBLK, 256, 0, stream>>>(deg2, bsum);
    k_scan_boff<<<1, 1024, 0, stream>>>(bsum, boff);
    k_scan_final<<<NBLK, 256, 0, stream>>>(deg2, boff, off2, cursor, g);
    k_fill<<<(EE + 255) / 256, 256, 0, stream>>>(dst, src, etype, cursor, csr_src);
    k_prep_w2f<<<(PREP_TOT + 255) / 256, 256, 0, stream>>>(W_msg, b_msg, w_ih, w_hh,
                                                           b_ih, b_hh, W2f, bias512);

    __hip_bfloat16* hbc = hbfA;
    __hip_bfloat16* hbx = hbfB;
    for (int s = 0; s < STEPS; ++s) {
        k_agg<<<(NN * 64 + 255) / 256, 256, 0, stream>>>(hbc, off2, csr_src, g);
        k_step<<<MT64, 512, 0, stream>>>(g, W2f, bias512, hbc, hbx);
        __hip_bfloat16* tb = hbc; hbc = hbx; hbx = tb;
    }
    k_readout<<<(NN + 63) / 64, 128, 0, stream>>>(hbc, hini, n2g, feats);
    k_cls<<<1, 128, 0, stream>>>(feats, W_cls, b_cls, out);
}